// Round 10
// baseline (849.006 us; speedup 1.0000x reference)
//
#include <hip/hip_runtime.h>
#include <math.h>

typedef __attribute__((ext_vector_type(8))) short short8;
typedef __attribute__((ext_vector_type(4))) float floatx4;

// fast sigmoid (no -ffast-math in harness): mul+exp+add+rcp
__device__ __forceinline__ float sig(float z) {
    return __builtin_amdgcn_rcpf(1.0f + __expf(-z));
}

__device__ __forceinline__ unsigned short f2bf(float f) {
    unsigned u = __float_as_uint(f);
    u = (u + 0x7FFFu + ((u >> 16) & 1u)) >> 16;
    return (unsigned short)u;
}

#if __has_builtin(__builtin_amdgcn_cvt_pk_bf16_f32)
typedef __attribute__((ext_vector_type(2))) short short2v;
__device__ __forceinline__ unsigned int pack2bf(float a, float b) {
    short2v r = __builtin_amdgcn_cvt_pk_bf16_f32(a, b);
    return *(unsigned int*)&r;
}
#else
__device__ __forceinline__ unsigned int pack2bf(float a, float b) {
    unsigned ua = __float_as_uint(a), ub = __float_as_uint(b);
    ua += 0x7FFFu + ((ua >> 16) & 1u);
    ub += 0x7FFFu + ((ub >> 16) & 1u);
    return __builtin_amdgcn_perm(ub, ua, 0x07060302);
}
#endif

// All four W1 matrices -> bf16 pre-swizzled MFMA 16x16x32 B-frag order.
// blk = (n>>4)*(H/32) + (k>>5), lane = ((k>>3)&3)*16 + (n&15), j = k&7.
__global__ void convert_all(const float* __restrict__ s0, const float* __restrict__ s1,
                            const float* __restrict__ s2, const float* __restrict__ s3,
                            unsigned short* __restrict__ ws) {
    int idx = blockIdx.x * 256 + threadIdx.x;          // 0 .. 458751
    const float* src; unsigned short* dst; int H, logH, local;
    if (idx < 262144) { src = s0; dst = ws; H = 512; logH = 9; local = idx; }
    else {
        int r = idx - 262144; int m = r >> 16; local = r & 65535;
        H = 256; logH = 8;
        src = (m == 0) ? s1 : (m == 1) ? s2 : s3;
        dst = ws + 262144 + m * 65536;
    }
    int n = local & (H - 1), k = local >> logH;
    int KT = H >> 5;
    int blk = (n >> 4) * KT + (k >> 5);
    int lane = ((k >> 3) & 3) * 16 + (n & 15);
    int j = k & 7;
    dst[(blk * 64 + lane) * 8 + j] = f2bf(src[local]);
}

// Persistent fused kernel. Grid = 1024 (even blocks: pos, 8 tiles x 4 samples;
// odd blocks: rpy, 12 tiles x 8 samples; head = tile/2048, re-staged on switch).
// Small acc tiles (64 AGPR) + once-per-block weight staging -> 3 waves/SIMD.
__global__ __launch_bounds__(256, 3)
void fused_persist(const float* __restrict__ x,
                   const float* __restrict__ pW0, const float* __restrict__ pb0,
                   const float* __restrict__ pb1,
                   const float* __restrict__ pW2, const float* __restrict__ pb2,
                   const float* __restrict__ rW0_, const float* __restrict__ rb0_,
                   const float* __restrict__ rb1_,
                   const float* __restrict__ rW2_, const float* __restrict__ rb2_,
                   const float* __restrict__ piW0, const float* __restrict__ pib0,
                   const float* __restrict__ pib1,
                   const float* __restrict__ piW2, const float* __restrict__ pib2,
                   const float* __restrict__ yW0, const float* __restrict__ yb0,
                   const float* __restrict__ yb1,
                   const float* __restrict__ yW2, const float* __restrict__ yb2,
                   const unsigned short* __restrict__ wsBase,
                   float* __restrict__ out, int ns)
{
    extern __shared__ unsigned short sA[];      // 16384 shorts = 32 KB
    __shared__ float sB0[512], sB1[512], sW2[1536];
    __shared__ float sQx[3][8][16];             // x ring: [slot][sample][q0..6,qd0..6]
    __shared__ float sScr[4][64][3];            // per-wave partials
    __shared__ float sSum[2][64][3];            // double-buffered final sums

    const int tid = threadIdx.x;
    const int w = tid >> 6, lane = tid & 63;
    const int quad = lane >> 4, col = lane & 15, srcl = lane & 47;
    const size_t JTOT = (size_t)ns * 18, OUTA = (size_t)ns * 81, JANG = (size_t)ns * 87;
    const floatx4 z4 = {0.f, 0.f, 0.f, 0.f};

    if ((blockIdx.x & 1) == 0) {
        // ================= POS persistent: 8 tiles of 4 samples =================
        const int pid = blockIdx.x >> 1;            // 0..511
        if (tid < 128) {
            ((float4*)sB0)[tid] = ((const float4*)pb0)[tid];
            ((float4*)sB1)[tid] = ((const float4*)pb1)[tid];
        }
        for (int j = tid; j < 384; j += 256) ((float4*)sW2)[j] = ((const float4*)pW2)[j];
        if (tid < 56) {
            int m = tid / 14, c = tid % 14;
            sQx[0][m][c] = x[((size_t)pid * 32 + m) * 14 + c];
        }
        __syncthreads();

        const float4* W04 = (const float4*)pW0;
        for (int k = 0; k < 8; ++k) {
            const int m0 = pid * 32 + k * 4;
            const int slot = k % 3;
            // ---- build A(k): 512 items (s 0..3, g 0..127), 4 k-vals each ----
            #pragma unroll
            for (int t = 0; t < 2; ++t) {
                int item = tid + t * 256;
                int s = item >> 7, gg = item & 127;
                int kt = gg >> 3, kq = (gg >> 1) & 3, j0 = (gg & 1) * 4;
                int sw = kt & 7;
                int kk = gg * 4;
                float q[7]; float4 w0r[7];
                #pragma unroll
                for (int i = 0; i < 7; i++) { q[i] = sQx[slot][s][i]; w0r[i] = W04[i * 128 + gg]; }
                float hv[4], dv[4];
                #pragma unroll
                for (int jj = 0; jj < 4; jj++) {
                    float z = sB0[kk + jj];
                    #pragma unroll
                    for (int i = 0; i < 7; i++) z = fmaf(q[i], ((const float*)&w0r[i])[jj], z);
                    float hh = sig(z);
                    hv[jj] = hh; dv[jj] = hh - hh * hh;
                }
                const int rt = s >> 1, rb = (s & 1) * 8;
                {
                    int cl = (kq * 16 + rb) ^ sw;
                    uint2 v; v.x = pack2bf(hv[0], hv[1]); v.y = pack2bf(hv[2], hv[3]);
                    *(uint2*)&sA[(rt * 16 + kt) * 512 + cl * 8 + j0] = v;
                }
                #pragma unroll
                for (int i = 0; i < 7; i++) {
                    int cl = (kq * 16 + rb + 1 + i) ^ sw;
                    uint2 v;
                    v.x = pack2bf(dv[0] * ((const float*)&w0r[i])[0], dv[1] * ((const float*)&w0r[i])[1]);
                    v.y = pack2bf(dv[2] * ((const float*)&w0r[i])[2], dv[3] * ((const float*)&w0r[i])[3]);
                    *(uint2*)&sA[(rt * 16 + kt) * 512 + cl * 8 + j0] = v;
                }
            }
            __syncthreads();                                     // b1: A ready
            // prefetch x(k+1)
            if (k + 1 < 8 && tid < 56) {
                int m = tid / 14, c = tid % 14;
                sQx[(k + 1) % 3][m][c] = x[((size_t)m0 + 4 + m) * 14 + c];
            }
            // ---- K loop ----
            floatx4 acc[2][8];
            #pragma unroll
            for (int rt = 0; rt < 2; rt++)
                #pragma unroll
                for (int ct = 0; ct < 8; ct++) acc[rt][ct] = z4;
            const short8* bbase = (const short8*)wsBase + (size_t)(w * 128) * 64 + lane;
            #pragma unroll
            for (int kt = 0; kt < 16; ++kt) {
                const int sw = kt & 7;
                short8 bf[8];
                #pragma unroll
                for (int ct = 0; ct < 8; ++ct) bf[ct] = bbase[(ct * 16 + kt) * 64];
                short8 a0 = *(const short8*)&sA[kt * 512 + (lane ^ sw) * 8];
                short8 a1 = *(const short8*)&sA[(16 + kt) * 512 + (lane ^ sw) * 8];
                #pragma unroll
                for (int ct = 0; ct < 8; ++ct) {
                    acc[0][ct] = __builtin_amdgcn_mfma_f32_16x16x32_bf16(a0, bf[ct], acc[0][ct], 0, 0, 0);
                    acc[1][ct] = __builtin_amdgcn_mfma_f32_16x16x32_bf16(a1, bf[ct], acc[1][ct], 0, 0, 0);
                }
            }
            // ---- epilogue part1 ----
            float ep[2][4][3];
            #pragma unroll
            for (int a = 0; a < 2; a++) for (int b = 0; b < 4; b++) for (int c = 0; c < 3; c++) ep[a][b][c] = 0.f;
            #pragma unroll
            for (int ct = 0; ct < 8; ++ct) {
                const int n = w * 128 + ct * 16 + col;
                const float b1n = sB1[n];
                const float w20 = sW2[n * 3], w21 = sW2[n * 3 + 1], w22 = sW2[n * 3 + 2];
                #pragma unroll
                for (int rt = 0; rt < 2; ++rt) {
                    float z2c = __shfl(acc[rt][ct][0], srcl);
                    float h2 = sig(z2c + b1n);
                    float d2 = h2 - h2 * h2;
                    #pragma unroll
                    for (int r = 0; r < 4; ++r) {
                        float gg2 = ((quad & 1) == 0 && r == 0) ? h2 : d2 * acc[rt][ct][r];
                        ep[rt][r][0] = fmaf(gg2, w20, ep[rt][r][0]);
                        ep[rt][r][1] = fmaf(gg2, w21, ep[rt][r][1]);
                        ep[rt][r][2] = fmaf(gg2, w22, ep[rt][r][2]);
                    }
                }
            }
            #pragma unroll
            for (int mask = 1; mask <= 8; mask <<= 1)
                #pragma unroll
                for (int a = 0; a < 2; a++)
                    #pragma unroll
                    for (int b = 0; b < 4; b++)
                        #pragma unroll
                        for (int c = 0; c < 3; c++)
                            ep[a][b][c] += __shfl_xor(ep[a][b][c], mask);
            if (col == 0) {
                #pragma unroll
                for (int rt = 0; rt < 2; ++rt)
                    #pragma unroll
                    for (int r = 0; r < 4; ++r) {
                        int row = rt * 16 + quad * 4 + r;
                        sScr[w][row][0] = ep[rt][r][0];
                        sScr[w][row][1] = ep[rt][r][1];
                        sScr[w][row][2] = ep[rt][r][2];
                    }
            }
            __syncthreads();                                     // b2: partials ready
            if (tid < 96) {
                int row = tid / 3, j = tid % 3;
                float v = sScr[0][row][j] + sScr[1][row][j] + sScr[2][row][j] + sScr[3][row][j];
                int i_row = row & 7, s = row >> 3;
                size_t M = m0 + s;
                if (i_row == 0) { v += pb2[j]; out[M * 18 + j] = v; out[OUTA + M * 6 + j] = v; }
                else            { out[JTOT + M * 63 + j * 7 + (i_row - 1)] = v;
                                  out[JANG + M * 42 + j * 7 + (i_row - 1)] = v; }
                sSum[k & 1][row][j] = v;
            }
            __syncthreads();                                     // b3: sums ready
            if (tid < 12) {
                int s = tid / 3, j = tid % 3;
                float vel = 0.f;
                #pragma unroll
                for (int i = 0; i < 7; i++)
                    vel = fmaf(sSum[k & 1][s * 8 + 1 + i][j], sQx[slot][s][7 + i], vel);
                out[(size_t)(m0 + s) * 18 + 9 + j] = vel;
            }
        }
    } else {
        // ================= RPY persistent: 12 tiles of 8 samples =================
        const int rid = blockIdx.x >> 1;            // 0..511
        int hcur = -1;
        const float* W0h = rW0_; const float* b1h = rb1_;
        const float* W2h = rW2_; const float* b2h = rb2_; const float* b0h = rb0_;
        const unsigned short* wsW1 = wsBase + 262144;
        {
            int t0 = rid * 12;
            int m00 = (t0 & 2047) * 8;
            if (tid < 112) {
                int m = tid / 14, c = tid % 14;
                sQx[0][m][c] = x[((size_t)m00 + m) * 14 + c];
            }
        }
        for (int k = 0; k < 12; ++k) {
            const int t = rid * 12 + k;
            const int h = t >> 11;
            const int m0 = (t & 2047) * 8;
            const int slot = k % 3;
            if (h != hcur) {
                W0h = (h == 0) ? rW0_ : (h == 1) ? piW0 : yW0;
                b0h = (h == 0) ? rb0_ : (h == 1) ? pib0 : yb0;
                b1h = (h == 0) ? rb1_ : (h == 1) ? pib1 : yb1;
                W2h = (h == 0) ? rW2_ : (h == 1) ? piW2 : yW2;
                b2h = (h == 0) ? rb2_ : (h == 1) ? pib2 : yb2;
                wsW1 = wsBase + 262144 + h * 65536;
                __syncthreads();
                if (tid < 64) {
                    ((float4*)sB0)[tid] = ((const float4*)b0h)[tid];
                    ((float4*)sB1)[tid] = ((const float4*)b1h)[tid];
                } else if (tid < 192) {
                    ((float4*)sW2)[tid - 64] = ((const float4*)W2h)[tid - 64];
                }
                hcur = h;
                __syncthreads();
            }
            const float4* W04 = (const float4*)W0h;
            // ---- build A(k): 512 items (s 0..7, g 0..63), 4 k-vals each ----
            #pragma unroll
            for (int tt = 0; tt < 2; ++tt) {
                int item = tid + tt * 256;
                int s = item >> 6, gg = item & 63;
                int kt = gg >> 3, kq = (gg >> 1) & 3, j0 = (gg & 1) * 4;
                int sw = kt & 7;
                int kk = gg * 4;
                float q[7]; float4 w0r[7];
                #pragma unroll
                for (int i = 0; i < 7; i++) { q[i] = sQx[slot][s][i]; w0r[i] = W04[i * 64 + gg]; }
                float hv[4], dv[4];
                #pragma unroll
                for (int jj = 0; jj < 4; jj++) {
                    float z = sB0[kk + jj];
                    #pragma unroll
                    for (int i = 0; i < 7; i++) z = fmaf(q[i], ((const float*)&w0r[i])[jj], z);
                    float hh = sig(z);
                    hv[jj] = hh; dv[jj] = hh - hh * hh;
                }
                const int rt = s >> 1, rb = (s & 1) * 8;
                {
                    int cl = (kq * 16 + rb) ^ sw;
                    uint2 v; v.x = pack2bf(hv[0], hv[1]); v.y = pack2bf(hv[2], hv[3]);
                    *(uint2*)&sA[(rt * 8 + kt) * 512 + cl * 8 + j0] = v;
                }
                #pragma unroll
                for (int i = 0; i < 7; i++) {
                    int cl = (kq * 16 + rb + 1 + i) ^ sw;
                    uint2 v;
                    v.x = pack2bf(dv[0] * ((const float*)&w0r[i])[0], dv[1] * ((const float*)&w0r[i])[1]);
                    v.y = pack2bf(dv[2] * ((const float*)&w0r[i])[2], dv[3] * ((const float*)&w0r[i])[3]);
                    *(uint2*)&sA[(rt * 8 + kt) * 512 + cl * 8 + j0] = v;
                }
            }
            __syncthreads();                                     // b1
            if (k + 1 < 12 && tid < 112) {
                int t2 = t + 1;
                int m = tid / 14, c = tid % 14;
                sQx[(k + 1) % 3][m][c] = x[((size_t)((t2 & 2047) * 8) + m) * 14 + c];
            }
            // ---- K loop ----
            floatx4 acc[4][4];
            #pragma unroll
            for (int rt = 0; rt < 4; rt++)
                #pragma unroll
                for (int ct = 0; ct < 4; ct++) acc[rt][ct] = z4;
            const short8* bbase = (const short8*)wsW1 + (size_t)(w * 32) * 64 + lane;
            #pragma unroll
            for (int kt = 0; kt < 8; ++kt) {
                const int sw = kt & 7;
                short8 bf[4];
                #pragma unroll
                for (int ct = 0; ct < 4; ++ct) bf[ct] = bbase[(ct * 8 + kt) * 64];
                short8 afr[4];
                #pragma unroll
                for (int rt = 0; rt < 4; ++rt)
                    afr[rt] = *(const short8*)&sA[(rt * 8 + kt) * 512 + (lane ^ sw) * 8];
                #pragma unroll
                for (int ct = 0; ct < 4; ++ct)
                    #pragma unroll
                    for (int rt = 0; rt < 4; ++rt)
                        acc[rt][ct] = __builtin_amdgcn_mfma_f32_16x16x32_bf16(afr[rt], bf[ct], acc[rt][ct], 0, 0, 0);
            }
            // ---- epilogue part1 ----
            float ep[4][4][2];
            #pragma unroll
            for (int a = 0; a < 4; a++) for (int b = 0; b < 4; b++) for (int c = 0; c < 2; c++) ep[a][b][c] = 0.f;
            #pragma unroll
            for (int ct = 0; ct < 4; ++ct) {
                const int n = w * 64 + ct * 16 + col;
                const float b1n = sB1[n];
                const float w20 = sW2[n * 2], w21 = sW2[n * 2 + 1];
                #pragma unroll
                for (int rt = 0; rt < 4; ++rt) {
                    float z2c = __shfl(acc[rt][ct][0], srcl);
                    float h2 = sig(z2c + b1n);
                    float d2 = h2 - h2 * h2;
                    #pragma unroll
                    for (int r = 0; r < 4; ++r) {
                        float gg2 = ((quad & 1) == 0 && r == 0) ? h2 : d2 * acc[rt][ct][r];
                        ep[rt][r][0] = fmaf(gg2, w20, ep[rt][r][0]);
                        ep[rt][r][1] = fmaf(gg2, w21, ep[rt][r][1]);
                    }
                }
            }
            #pragma unroll
            for (int mask = 1; mask <= 8; mask <<= 1)
                #pragma unroll
                for (int a = 0; a < 4; a++)
                    #pragma unroll
                    for (int b = 0; b < 4; b++)
                        #pragma unroll
                        for (int c = 0; c < 2; c++)
                            ep[a][b][c] += __shfl_xor(ep[a][b][c], mask);
            if (col == 0) {
                #pragma unroll
                for (int rt = 0; rt < 4; ++rt)
                    #pragma unroll
                    for (int r = 0; r < 4; ++r) {
                        int row = rt * 16 + quad * 4 + r;
                        sScr[w][row][0] = ep[rt][r][0];
                        sScr[w][row][1] = ep[rt][r][1];
                    }
            }
            __syncthreads();                                     // b2
            if (tid < 128) {
                int row = tid >> 1, j = tid & 1;
                float v = sScr[0][row][j] + sScr[1][row][j] + sScr[2][row][j] + sScr[3][row][j];
                if ((row & 7) == 0) v += b2h[j];
                sSum[k & 1][row][j] = v;
            }
            __syncthreads();                                     // b3
            if (tid < 8) {
                int s = tid;
                size_t M = m0 + s;
                float y0 = sSum[k & 1][s * 8][0], y1 = sSum[k & 1][s * 8][1];
                float sv = sinf(y0), cv = cosf(y1);
                out[M * 18 + 3 + h] = sv;
                out[M * 18 + 6 + h] = cv;
                out[OUTA + M * 6 + 3 + h] = atan2f(sv, cv);
                float f0 = cosf(y0), f1 = -sinf(y1);
                float inv = __builtin_amdgcn_rcpf(fmaf(sv, sv, cv * cv));
                float v0 = 0.f, v1 = 0.f;
                #pragma unroll
                for (int i = 0; i < 7; i++) {
                    float r0 = f0 * sSum[k & 1][s * 8 + 1 + i][0];
                    float r1 = f1 * sSum[k & 1][s * 8 + 1 + i][1];
                    out[JTOT + M * 63 + (3 + h) * 7 + i] = r0;
                    out[JTOT + M * 63 + (6 + h) * 7 + i] = r1;
                    out[JANG + M * 42 + (3 + h) * 7 + i] = (cv * r0 - sv * r1) * inv;
                    v0 = fmaf(r0, sQx[slot][s][7 + i], v0);
                    v1 = fmaf(r1, sQx[slot][s][7 + i], v1);
                }
                out[M * 18 + 12 + h] = v0;
                out[M * 18 + 15 + h] = v1;
            }
        }
    }
}

extern "C" void kernel_launch(void* const* d_in, const int* in_sizes, int n_in,
                              void* d_out, int out_size, void* d_ws, size_t ws_size,
                              hipStream_t stream) {
    (void)n_in; (void)out_size; (void)ws_size;
    const float* x = (const float*)d_in[0];
    float* out = (float*)d_out;
    unsigned short* ws = (unsigned short*)d_ws;
    const int ns = in_sizes[0] / 14;

    convert_all<<<dim3(1792), 256, 0, stream>>>(
        (const float*)d_in[3], (const float*)d_in[9],
        (const float*)d_in[15], (const float*)d_in[21], ws);

    // 1024 persistent blocks: even = pos (512 x 8 tiles x 4 samples),
    // odd = rpy (512 x 12 tiles x 8 samples, heads packed contiguously)
    fused_persist<<<dim3((ns / 32) * 2), 256, 32768, stream>>>(
        x,
        (const float*)d_in[1],  (const float*)d_in[2],  (const float*)d_in[4],
        (const float*)d_in[5],  (const float*)d_in[6],
        (const float*)d_in[7],  (const float*)d_in[8],  (const float*)d_in[10],
        (const float*)d_in[11], (const float*)d_in[12],
        (const float*)d_in[13], (const float*)d_in[14], (const float*)d_in[16],
        (const float*)d_in[17], (const float*)d_in[18],
        (const float*)d_in[19], (const float*)d_in[20], (const float*)d_in[22],
        (const float*)d_in[23], (const float*)d_in[24],
        ws, out, ns);
}

// Round 11
// 773.321 us; speedup vs baseline: 1.0979x; 1.0979x over previous
//
#include <hip/hip_runtime.h>
#include <math.h>

typedef __attribute__((ext_vector_type(8))) short short8;
typedef __attribute__((ext_vector_type(4))) float floatx4;

// fast sigmoid (no -ffast-math in harness): mul+exp+add+rcp
__device__ __forceinline__ float sig(float z) {
    return __builtin_amdgcn_rcpf(1.0f + __expf(-z));
}

__device__ __forceinline__ unsigned short f2bf(float f) {
    unsigned u = __float_as_uint(f);
    u = (u + 0x7FFFu + ((u >> 16) & 1u)) >> 16;
    return (unsigned short)u;
}

#if __has_builtin(__builtin_amdgcn_cvt_pk_bf16_f32)
typedef __attribute__((ext_vector_type(2))) short short2v;
__device__ __forceinline__ unsigned int pack2bf(float a, float b) {
    short2v r = __builtin_amdgcn_cvt_pk_bf16_f32(a, b);
    return *(unsigned int*)&r;
}
#else
__device__ __forceinline__ unsigned int pack2bf(float a, float b) {
    unsigned ua = __float_as_uint(a), ub = __float_as_uint(b);
    ua += 0x7FFFu + ((ua >> 16) & 1u);
    ub += 0x7FFFu + ((ub >> 16) & 1u);
    return __builtin_amdgcn_perm(ub, ua, 0x07060302);
}
#endif

// All four W1 matrices -> bf16 pre-swizzled MFMA 16x16x32 B-frag order.
__global__ void convert_all(const float* __restrict__ s0, const float* __restrict__ s1,
                            const float* __restrict__ s2, const float* __restrict__ s3,
                            unsigned short* __restrict__ ws) {
    int idx = blockIdx.x * 256 + threadIdx.x;          // 0 .. 458751
    const float* src; unsigned short* dst; int H, logH, local;
    if (idx < 262144) { src = s0; dst = ws; H = 512; logH = 9; local = idx; }
    else {
        int r = idx - 262144; int m = r >> 16; local = r & 65535;
        H = 256; logH = 8;
        src = (m == 0) ? s1 : (m == 1) ? s2 : s3;
        dst = ws + 262144 + m * 65536;
    }
    int n = local & (H - 1), k = local >> logH;
    int KT = H >> 5;
    int blk = (n >> 4) * KT + (k >> 5);
    int lane = ((k >> 3) & 3) * 16 + (n & 15);
    int j = k & 7;
    dst[(blk * 64 + lane) * 8 + j] = f2bf(src[local]);
}

struct PosS {
    float B0[512], B1[512];
    float Qx[2][8][16];             // [buf][sample][q0..6,qd0..6]
    float Acc[4][64][3], Sum[64][3];
};
struct RpyS {
    float B0[256], B1[256];
    float Qx[2][16][16];
    float Acc[4][128][2], Sum[128][2];
};

// Fused, 2 sub-tiles per block. Group g (5 blocks) covers samples [32g,32g+32)
// for pos AND all rpy heads -> same-sample writers stay adjacent in dispatch
// (avoids the R10 cross-XCD out-line bounce). Statics ~9.2 KB + 64 KB dyn ->
// 2 blocks/CU with ~14 KB LDS slack.
__global__ __launch_bounds__(256, 2)
void fused_mfma(const float* __restrict__ x,
                const float* __restrict__ pW0, const float* __restrict__ pb0,
                const float* __restrict__ pb1,
                const float* __restrict__ pW2, const float* __restrict__ pb2,
                const float* __restrict__ rW0_, const float* __restrict__ rb0_,
                const float* __restrict__ rb1_,
                const float* __restrict__ rW2_, const float* __restrict__ rb2_,
                const float* __restrict__ piW0, const float* __restrict__ pib0,
                const float* __restrict__ pib1,
                const float* __restrict__ piW2, const float* __restrict__ pib2,
                const float* __restrict__ yW0, const float* __restrict__ yb0,
                const float* __restrict__ yb1,
                const float* __restrict__ yW2, const float* __restrict__ yb2,
                const unsigned short* __restrict__ wsBase,
                float* __restrict__ out, int ns)
{
    extern __shared__ unsigned short sA[];      // 64 KB dynamic
    __shared__ union { PosS p; RpyS r; } sU;

    const int tid = threadIdx.x;
    const int f = blockIdx.x;
    const int g = f / 5, r5 = f % 5;
    const size_t JTOT = (size_t)ns * 18, OUTA = (size_t)ns * 81, JANG = (size_t)ns * 87;
    const floatx4 z4 = {0.f, 0.f, 0.f, 0.f};
    const int w = tid >> 6, lane = tid & 63;
    const int quad = lane >> 4, col = lane & 15;
    const int srcl = lane & 47;

    if (r5 < 2) {
        // ===== POS: 7 -> 512 -> 512 -> 3; 2 sub-tiles x 8 samples =====
        const int m_base = g * 32 + r5 * 16;
        const unsigned short* wsW1 = wsBase;

        if (tid < 128) {
            ((float4*)sU.p.B0)[tid] = ((const float4*)pb0)[tid];
            ((float4*)sU.p.B1)[tid] = ((const float4*)pb1)[tid];
        }
        if (tid < 112) {
            int m = tid / 14, c = tid % 14;
            sU.p.Qx[0][m][c] = x[((size_t)m_base + m) * 14 + c];
        }
        __syncthreads();

        const float4* W04 = (const float4*)pW0;
        for (int st = 0; st < 2; ++st) {
            const int m0 = m_base + st * 8;
            const int buf = st & 1;
            // ---- build A ----
            #pragma unroll
            for (int t = 0; t < 2; ++t) {
                int item = tid + t * 256;
                int s = item >> 6, k8 = item & 63;
                float q[7], w0v[7][8];
                #pragma unroll
                for (int i = 0; i < 7; i++) {
                    q[i] = sU.p.Qx[buf][s][i];
                    float4 a = W04[i * 128 + k8 * 2], b4 = W04[i * 128 + k8 * 2 + 1];
                    w0v[i][0]=a.x; w0v[i][1]=a.y; w0v[i][2]=a.z; w0v[i][3]=a.w;
                    w0v[i][4]=b4.x; w0v[i][5]=b4.y; w0v[i][6]=b4.z; w0v[i][7]=b4.w;
                }
                float hv[8], dv[8];
                #pragma unroll
                for (int jj = 0; jj < 8; jj++) {
                    float z = sU.p.B0[k8 * 8 + jj];
                    #pragma unroll
                    for (int i = 0; i < 7; i++) z = fmaf(q[i], w0v[i][jj], z);
                    float h = sig(z);
                    hv[jj] = h; dv[jj] = h - h * h;
                }
                int kt = k8 >> 2, kq = k8 & 3, sw = kt & 7;
                int rr0 = s * 8;
                {
                    uint4 v;
                    v.x = pack2bf(hv[0], hv[1]); v.y = pack2bf(hv[2], hv[3]);
                    v.z = pack2bf(hv[4], hv[5]); v.w = pack2bf(hv[6], hv[7]);
                    *(uint4*)&sA[((rr0 >> 4) * 16 + kt) * 512 + ((kq * 16 + (rr0 & 15)) ^ sw) * 8] = v;
                }
                #pragma unroll
                for (int i = 0; i < 7; i++) {
                    int rr = rr0 + 1 + i;
                    uint4 v;
                    v.x = pack2bf(dv[0] * w0v[i][0], dv[1] * w0v[i][1]);
                    v.y = pack2bf(dv[2] * w0v[i][2], dv[3] * w0v[i][3]);
                    v.z = pack2bf(dv[4] * w0v[i][4], dv[5] * w0v[i][5]);
                    v.w = pack2bf(dv[6] * w0v[i][6], dv[7] * w0v[i][7]);
                    *(uint4*)&sA[((rr >> 4) * 16 + kt) * 512 + ((kq * 16 + (rr & 15)) ^ sw) * 8] = v;
                }
            }
            __syncthreads();                                 // B1: A ready
            if (st + 1 < 2 && tid < 112) {
                int m = tid / 14, c = tid % 14;
                sU.p.Qx[1][m][c] = x[((size_t)m_base + 8 + m) * 14 + c];
            }
            // ---- K loop (B register ping-pong) ----
            floatx4 acc[4][8];
            #pragma unroll
            for (int rt = 0; rt < 4; rt++)
                #pragma unroll
                for (int ct = 0; ct < 8; ct++) acc[rt][ct] = z4;

            const short8* bbase = (const short8*)wsW1 + (size_t)(w * 8 * 16) * 64 + lane;
            short8 bufA[8], bufB[8];
            #pragma unroll
            for (int ct = 0; ct < 8; ++ct) bufA[ct] = bbase[(ct * 16) * 64];
            for (int kt2 = 0; kt2 < 16; kt2 += 2) {
                #pragma unroll
                for (int ct = 0; ct < 8; ++ct) bufB[ct] = bbase[(ct * 16 + kt2 + 1) * 64];
                {
                    const int kt = kt2, sw = kt & 7;
                    short8 afr[4];
                    #pragma unroll
                    for (int rt = 0; rt < 4; ++rt)
                        afr[rt] = *(const short8*)&sA[(rt * 16 + kt) * 512 + (lane ^ sw) * 8];
                    #pragma unroll
                    for (int ct = 0; ct < 8; ++ct)
                        #pragma unroll
                        for (int rt = 0; rt < 4; ++rt)
                            acc[rt][ct] = __builtin_amdgcn_mfma_f32_16x16x32_bf16(afr[rt], bufA[ct], acc[rt][ct], 0, 0, 0);
                }
                if (kt2 + 2 < 16) {
                    #pragma unroll
                    for (int ct = 0; ct < 8; ++ct) bufA[ct] = bbase[(ct * 16 + kt2 + 2) * 64];
                }
                {
                    const int kt = kt2 + 1, sw = kt & 7;
                    short8 afr[4];
                    #pragma unroll
                    for (int rt = 0; rt < 4; ++rt)
                        afr[rt] = *(const short8*)&sA[(rt * 16 + kt) * 512 + (lane ^ sw) * 8];
                    #pragma unroll
                    for (int ct = 0; ct < 8; ++ct)
                        #pragma unroll
                        for (int rt = 0; rt < 4; ++rt)
                            acc[rt][ct] = __builtin_amdgcn_mfma_f32_16x16x32_bf16(afr[rt], bufB[ct], acc[rt][ct], 0, 0, 0);
                }
            }
            // ---- epilogue ----
            float ep[4][4][3];
            #pragma unroll
            for (int a = 0; a < 4; a++) for (int b = 0; b < 4; b++) for (int c = 0; c < 3; c++) ep[a][b][c] = 0.f;
            #pragma unroll
            for (int ct = 0; ct < 8; ++ct) {
                const int n = w * 128 + ct * 16 + col;
                const float b1n = sU.p.B1[n];
                const float w20 = pW2[n * 3], w21 = pW2[n * 3 + 1], w22 = pW2[n * 3 + 2];
                #pragma unroll
                for (int rt = 0; rt < 4; ++rt) {
                    float z2c = __shfl(acc[rt][ct][0], srcl);
                    float h2 = sig(z2c + b1n);
                    float d2 = h2 - h2 * h2;
                    #pragma unroll
                    for (int r = 0; r < 4; ++r) {
                        float gg = ((quad & 1) == 0 && r == 0) ? h2 : d2 * acc[rt][ct][r];
                        ep[rt][r][0] = fmaf(gg, w20, ep[rt][r][0]);
                        ep[rt][r][1] = fmaf(gg, w21, ep[rt][r][1]);
                        ep[rt][r][2] = fmaf(gg, w22, ep[rt][r][2]);
                    }
                }
            }
            #pragma unroll
            for (int mask = 1; mask <= 8; mask <<= 1)
                #pragma unroll
                for (int a = 0; a < 4; a++)
                    #pragma unroll
                    for (int b = 0; b < 4; b++)
                        #pragma unroll
                        for (int c = 0; c < 3; c++)
                            ep[a][b][c] += __shfl_xor(ep[a][b][c], mask);
            if (col == 0) {
                #pragma unroll
                for (int rt = 0; rt < 4; ++rt)
                    #pragma unroll
                    for (int r = 0; r < 4; ++r) {
                        int row = rt * 16 + quad * 4 + r;
                        sU.p.Acc[w][row][0] = ep[rt][r][0];
                        sU.p.Acc[w][row][1] = ep[rt][r][1];
                        sU.p.Acc[w][row][2] = ep[rt][r][2];
                    }
            }
            __syncthreads();                                 // B2: Acc ready, sA free
            if (tid < 192) {
                int row = tid / 3, j = tid % 3;
                float v = sU.p.Acc[0][row][j] + sU.p.Acc[1][row][j] + sU.p.Acc[2][row][j] + sU.p.Acc[3][row][j];
                int s = row >> 3, i = row & 7;
                size_t M = m0 + s;
                if (i == 0) { v += pb2[j]; out[M * 18 + j] = v; out[OUTA + M * 6 + j] = v; }
                else        { out[JTOT + M * 63 + j * 7 + (i - 1)] = v;
                              out[JANG + M * 42 + j * 7 + (i - 1)] = v; }
                sU.p.Sum[row][j] = v;
            }
            __syncthreads();                                 // B3: Sum ready
            if (tid < 24) {
                int s = tid / 3, j = tid % 3;
                float vel = 0.f;
                #pragma unroll
                for (int i = 0; i < 7; i++) vel = fmaf(sU.p.Sum[s * 8 + 1 + i][j], sU.p.Qx[buf][s][7 + i], vel);
                out[(size_t)(m0 + s) * 18 + 9 + j] = vel;
            }
        }
    } else {
        // ===== RPY head h: 7 -> 256 -> 256 -> 2; 2 sub-tiles x 16 samples =====
        const int h = r5 - 2;
        const int m_base = g * 32;
        const float* W0 = (h == 0) ? rW0_ : (h == 1) ? piW0 : yW0;
        const float* b0 = (h == 0) ? rb0_ : (h == 1) ? pib0 : yb0;
        const float* b1 = (h == 0) ? rb1_ : (h == 1) ? pib1 : yb1;
        const float* W2 = (h == 0) ? rW2_ : (h == 1) ? piW2 : yW2;
        const float* b2 = (h == 0) ? rb2_ : (h == 1) ? pib2 : yb2;
        const unsigned short* wsW1 = wsBase + 262144 + h * 65536;

        if (tid < 64) {
            ((float4*)sU.r.B0)[tid] = ((const float4*)b0)[tid];
            ((float4*)sU.r.B1)[tid] = ((const float4*)b1)[tid];
        }
        if (tid < 224) {
            int m = tid / 14, c = tid % 14;
            sU.r.Qx[0][m][c] = x[((size_t)m_base + m) * 14 + c];
        }
        __syncthreads();

        const float4* W04 = (const float4*)W0;
        for (int st = 0; st < 2; ++st) {
            const int m0 = m_base + st * 16;
            const int buf = st & 1;
            #pragma unroll
            for (int t = 0; t < 2; ++t) {
                int item = tid + t * 256;
                int s = item >> 5, k8 = item & 31;
                float q[7], w0v[7][8];
                #pragma unroll
                for (int i = 0; i < 7; i++) {
                    q[i] = sU.r.Qx[buf][s][i];
                    float4 a = W04[i * 64 + k8 * 2], b4 = W04[i * 64 + k8 * 2 + 1];
                    w0v[i][0]=a.x; w0v[i][1]=a.y; w0v[i][2]=a.z; w0v[i][3]=a.w;
                    w0v[i][4]=b4.x; w0v[i][5]=b4.y; w0v[i][6]=b4.z; w0v[i][7]=b4.w;
                }
                float hv[8], dv[8];
                #pragma unroll
                for (int jj = 0; jj < 8; jj++) {
                    float z = sU.r.B0[k8 * 8 + jj];
                    #pragma unroll
                    for (int i = 0; i < 7; i++) z = fmaf(q[i], w0v[i][jj], z);
                    float hh = sig(z);
                    hv[jj] = hh; dv[jj] = hh - hh * hh;
                }
                int kt = k8 >> 2, kq = k8 & 3, sw = kt & 7;
                int rr0 = s * 8;
                {
                    uint4 v;
                    v.x = pack2bf(hv[0], hv[1]); v.y = pack2bf(hv[2], hv[3]);
                    v.z = pack2bf(hv[4], hv[5]); v.w = pack2bf(hv[6], hv[7]);
                    *(uint4*)&sA[((rr0 >> 4) * 8 + kt) * 512 + ((kq * 16 + (rr0 & 15)) ^ sw) * 8] = v;
                }
                #pragma unroll
                for (int i = 0; i < 7; i++) {
                    int rr = rr0 + 1 + i;
                    uint4 v;
                    v.x = pack2bf(dv[0] * w0v[i][0], dv[1] * w0v[i][1]);
                    v.y = pack2bf(dv[2] * w0v[i][2], dv[3] * w0v[i][3]);
                    v.z = pack2bf(dv[4] * w0v[i][4], dv[5] * w0v[i][5]);
                    v.w = pack2bf(dv[6] * w0v[i][6], dv[7] * w0v[i][7]);
                    *(uint4*)&sA[((rr >> 4) * 8 + kt) * 512 + ((kq * 16 + (rr & 15)) ^ sw) * 8] = v;
                }
            }
            __syncthreads();                                 // B1
            if (st + 1 < 2 && tid < 224) {
                int m = tid / 14, c = tid % 14;
                sU.r.Qx[1][m][c] = x[((size_t)m_base + 16 + m) * 14 + c];
            }
            floatx4 acc[8][4];
            #pragma unroll
            for (int rt = 0; rt < 8; rt++)
                #pragma unroll
                for (int ct = 0; ct < 4; ct++) acc[rt][ct] = z4;

            const short8* bbase = (const short8*)wsW1 + (size_t)(w * 4 * 8) * 64 + lane;
            short8 bufA[4], bufB[4];
            #pragma unroll
            for (int ct = 0; ct < 4; ++ct) bufA[ct] = bbase[(ct * 8) * 64];
            for (int kt2 = 0; kt2 < 8; kt2 += 2) {
                #pragma unroll
                for (int ct = 0; ct < 4; ++ct) bufB[ct] = bbase[(ct * 8 + kt2 + 1) * 64];
                {
                    const int kt = kt2, sw = kt & 7;
                    short8 afr[8];
                    #pragma unroll
                    for (int rt = 0; rt < 8; ++rt)
                        afr[rt] = *(const short8*)&sA[(rt * 8 + kt) * 512 + (lane ^ sw) * 8];
                    #pragma unroll
                    for (int ct = 0; ct < 4; ++ct)
                        #pragma unroll
                        for (int rt = 0; rt < 8; ++rt)
                            acc[rt][ct] = __builtin_amdgcn_mfma_f32_16x16x32_bf16(afr[rt], bufA[ct], acc[rt][ct], 0, 0, 0);
                }
                if (kt2 + 2 < 8) {
                    #pragma unroll
                    for (int ct = 0; ct < 4; ++ct) bufA[ct] = bbase[(ct * 8 + kt2 + 2) * 64];
                }
                {
                    const int kt = kt2 + 1, sw = kt & 7;
                    short8 afr[8];
                    #pragma unroll
                    for (int rt = 0; rt < 8; ++rt)
                        afr[rt] = *(const short8*)&sA[(rt * 8 + kt) * 512 + (lane ^ sw) * 8];
                    #pragma unroll
                    for (int ct = 0; ct < 4; ++ct)
                        #pragma unroll
                        for (int rt = 0; rt < 8; ++rt)
                            acc[rt][ct] = __builtin_amdgcn_mfma_f32_16x16x32_bf16(afr[rt], bufB[ct], acc[rt][ct], 0, 0, 0);
                }
            }
            float ep[8][4][2];
            #pragma unroll
            for (int a = 0; a < 8; a++) for (int b = 0; b < 4; b++) for (int c = 0; c < 2; c++) ep[a][b][c] = 0.f;
            #pragma unroll
            for (int ct = 0; ct < 4; ++ct) {
                const int n = w * 64 + ct * 16 + col;
                const float b1n = sU.r.B1[n];
                const float w20 = W2[n * 2], w21 = W2[n * 2 + 1];
                #pragma unroll
                for (int rt = 0; rt < 8; ++rt) {
                    float z2c = __shfl(acc[rt][ct][0], srcl);
                    float h2 = sig(z2c + b1n);
                    float d2 = h2 - h2 * h2;
                    #pragma unroll
                    for (int r = 0; r < 4; ++r) {
                        float gg = ((quad & 1) == 0 && r == 0) ? h2 : d2 * acc[rt][ct][r];
                        ep[rt][r][0] = fmaf(gg, w20, ep[rt][r][0]);
                        ep[rt][r][1] = fmaf(gg, w21, ep[rt][r][1]);
                    }
                }
            }
            #pragma unroll
            for (int mask = 1; mask <= 8; mask <<= 1)
                #pragma unroll
                for (int a = 0; a < 8; a++)
                    #pragma unroll
                    for (int b = 0; b < 4; b++)
                        #pragma unroll
                        for (int c = 0; c < 2; c++)
                            ep[a][b][c] += __shfl_xor(ep[a][b][c], mask);
            if (col == 0) {
                #pragma unroll
                for (int rt = 0; rt < 8; ++rt)
                    #pragma unroll
                    for (int r = 0; r < 4; ++r) {
                        int row = rt * 16 + quad * 4 + r;
                        sU.r.Acc[w][row][0] = ep[rt][r][0];
                        sU.r.Acc[w][row][1] = ep[rt][r][1];
                    }
            }
            __syncthreads();                                 // B2
            if (tid < 256) {
                int row = tid >> 1, j = tid & 1;
                float v = sU.r.Acc[0][row][j] + sU.r.Acc[1][row][j] + sU.r.Acc[2][row][j] + sU.r.Acc[3][row][j];
                if ((row & 7) == 0) v += b2[j];
                sU.r.Sum[row][j] = v;
            }
            __syncthreads();                                 // B3
            if (tid < 16) {
                int s = tid;
                size_t M = m0 + s;
                float y0 = sU.r.Sum[s * 8][0], y1 = sU.r.Sum[s * 8][1];
                float sv = sinf(y0), cv = cosf(y1);
                out[M * 18 + 3 + h] = sv;
                out[M * 18 + 6 + h] = cv;
                out[OUTA + M * 6 + 3 + h] = atan2f(sv, cv);
                float f0 = cosf(y0), f1 = -sinf(y1);
                float inv = __builtin_amdgcn_rcpf(fmaf(sv, sv, cv * cv));
                float v0 = 0.f, v1 = 0.f;
                #pragma unroll
                for (int i = 0; i < 7; i++) {
                    float r0 = f0 * sU.r.Sum[s * 8 + 1 + i][0];
                    float r1 = f1 * sU.r.Sum[s * 8 + 1 + i][1];
                    out[JTOT + M * 63 + (3 + h) * 7 + i] = r0;
                    out[JTOT + M * 63 + (6 + h) * 7 + i] = r1;
                    out[JANG + M * 42 + (3 + h) * 7 + i] = (cv * r0 - sv * r1) * inv;
                    v0 = fmaf(r0, sU.r.Qx[buf][s][7 + i], v0);
                    v1 = fmaf(r1, sU.r.Qx[buf][s][7 + i], v1);
                }
                out[M * 18 + 12 + h] = v0;
                out[M * 18 + 15 + h] = v1;
            }
        }
    }
}

extern "C" void kernel_launch(void* const* d_in, const int* in_sizes, int n_in,
                              void* d_out, int out_size, void* d_ws, size_t ws_size,
                              hipStream_t stream) {
    (void)n_in; (void)out_size; (void)ws_size;
    const float* x = (const float*)d_in[0];
    float* out = (float*)d_out;
    unsigned short* ws = (unsigned short*)d_ws;
    const int ns = in_sizes[0] / 14;

    convert_all<<<dim3(1792), 256, 0, stream>>>(
        (const float*)d_in[3], (const float*)d_in[9],
        (const float*)d_in[15], (const float*)d_in[21], ws);

    // 2560 blocks: group of 5 covers samples [32g, 32g+32) for pos(2) + rpy(3)
    fused_mfma<<<dim3((ns / 32) * 5), 256, 65536, stream>>>(
        x,
        (const float*)d_in[1],  (const float*)d_in[2],  (const float*)d_in[4],
        (const float*)d_in[5],  (const float*)d_in[6],
        (const float*)d_in[7],  (const float*)d_in[8],  (const float*)d_in[10],
        (const float*)d_in[11], (const float*)d_in[12],
        (const float*)d_in[13], (const float*)d_in[14], (const float*)d_in[16],
        (const float*)d_in[17], (const float*)d_in[18],
        (const float*)d_in[19], (const float*)d_in[20], (const float*)d_in[22],
        (const float*)d_in[23], (const float*)d_in[24],
        ws, out, ns);
}

// Round 12
// 331.703 us; speedup vs baseline: 2.5595x; 2.3314x over previous
//
#include <hip/hip_runtime.h>
#include <math.h>

typedef __attribute__((ext_vector_type(8))) short short8;
typedef __attribute__((ext_vector_type(4))) float floatx4;

__device__ __forceinline__ float sig(float z) { return 1.0f / (1.0f + __expf(-z)); }

__device__ __forceinline__ unsigned short f2bf(float f) {
    unsigned u = __float_as_uint(f);
    u = (u + 0x7FFFu + ((u >> 16) & 1u)) >> 16;   // RNE
    return (unsigned short)u;
}

// All four W1 matrices -> bf16 pre-swizzled MFMA 16x16x32 B-frag order.
// blk = (n>>4)*(H/32) + (k>>5), lane = ((k>>3)&3)*16 + (n&15), j = k&7.
__global__ void convert_all(const float* __restrict__ s0, const float* __restrict__ s1,
                            const float* __restrict__ s2, const float* __restrict__ s3,
                            unsigned short* __restrict__ ws) {
    int idx = blockIdx.x * 256 + threadIdx.x;          // 0 .. 458751
    const float* src; unsigned short* dst; int H, logH, local;
    if (idx < 262144) { src = s0; dst = ws; H = 512; logH = 9; local = idx; }
    else {
        int r = idx - 262144; int m = r >> 16; local = r & 65535;
        H = 256; logH = 8;
        src = (m == 0) ? s1 : (m == 1) ? s2 : s3;
        dst = ws + 262144 + m * 65536;
    }
    int n = local & (H - 1), k = local >> logH;
    int KT = H >> 5;
    int blk = (n >> 4) * KT + (k >> 5);
    int lane = ((k >> 3) & 3) * 16 + (n & 15);
    int j = k & 7;
    dst[(blk * 64 + lane) * 8 + j] = f2bf(src[local]);
}

struct PosS {
    float B0[512], B1[512], W2[1536];
    float Q[8][8], Qd[8][8];
    float Acc[4][64][3], Sum[64][3];
};
struct RpyS {
    float B0[256], B1[256], W2[512];
    float Q[16][8], Qd[16][8];
    float Acc[4][128][2], Sum[128][2];
};

// Fused kernel (R7 body, measured 335.9 us): 5120 blocks; role r5<2 -> pos tile
// (8 samples), r5>=2 -> rpy head (16 samples).
// NEW: XCD-colocated group remap. Assuming round-robin block->XCD (i%8), all 5
// roles of sample-group g land on XCD g%8 in consecutive slots, so the four
// co-writers of each output cache line share one L2 (kills the R10/R11
// cross-XCD partial-line bounce; R7 still paid ~4.5x write amplification).
__global__ __launch_bounds__(256, 2)
void fused_mfma(const float* __restrict__ x,
                const float* __restrict__ pW0, const float* __restrict__ pb0,
                const float* __restrict__ pb1,
                const float* __restrict__ pW2, const float* __restrict__ pb2,
                const float* __restrict__ rW0_, const float* __restrict__ rb0_,
                const float* __restrict__ rb1_,
                const float* __restrict__ rW2_, const float* __restrict__ rb2_,
                const float* __restrict__ piW0, const float* __restrict__ pib0,
                const float* __restrict__ pib1,
                const float* __restrict__ piW2, const float* __restrict__ pib2,
                const float* __restrict__ yW0, const float* __restrict__ yb0,
                const float* __restrict__ yb1,
                const float* __restrict__ yW2, const float* __restrict__ yb2,
                const unsigned short* __restrict__ wsBase,
                float* __restrict__ out, int ns)
{
    extern __shared__ unsigned short sA[];      // 64 KB dynamic
    __shared__ union { PosS p; RpyS r; } sU;

    const int tid = threadIdx.x;
    // ---- XCD-colocation remap (bijection on 0..5119) ----
    const int xcd  = blockIdx.x & 7;
    const int slot = blockIdx.x >> 3;           // 0..639 within this XCD
    const int gidx = slot / 5, r5 = slot % 5;
    const int g = xcd + (gidx << 3);            // group 0..1023, all 5 roles on one XCD

    const size_t JTOT = (size_t)ns * 18, OUTA = (size_t)ns * 81, JANG = (size_t)ns * 87;
    const floatx4 z4 = {0.f, 0.f, 0.f, 0.f};
    const int w = tid >> 6, lane = tid & 63;
    const int quad = lane >> 4, col = lane & 15;
    const int srcl = lane & 47;

    if (r5 < 2) {
        // ================= POS: 7 -> 512 -> 512 -> 3, 8 samples =================
        const int m0 = (g * 2 + r5) * 8;
        const unsigned short* wsW1 = wsBase;

        for (int i = tid; i < 512;  i += 256) { sU.p.B0[i] = pb0[i]; sU.p.B1[i] = pb1[i]; }
        for (int i = tid; i < 1536; i += 256) sU.p.W2[i] = pW2[i];
        if (tid < 112) {
            int m = tid / 14, c = tid % 14;
            float v = x[(m0 + m) * 14 + c];
            if (c < 7) sU.p.Q[m][c] = v; else sU.p.Qd[m][c - 7] = v;
        }
        __syncthreads();

        const float4* W04 = (const float4*)pW0;
        #pragma unroll
        for (int t = 0; t < 2; ++t) {
            int item = tid + t * 256;
            int s = item >> 6, k8 = item & 63;
            float q[7], w0v[7][8];
            #pragma unroll
            for (int i = 0; i < 7; i++) {
                q[i] = sU.p.Q[s][i];
                float4 a = W04[i * 128 + k8 * 2], b4 = W04[i * 128 + k8 * 2 + 1];
                w0v[i][0]=a.x; w0v[i][1]=a.y; w0v[i][2]=a.z; w0v[i][3]=a.w;
                w0v[i][4]=b4.x; w0v[i][5]=b4.y; w0v[i][6]=b4.z; w0v[i][7]=b4.w;
            }
            float hv[8], dv[8];
            #pragma unroll
            for (int jj = 0; jj < 8; jj++) {
                float z = sU.p.B0[k8 * 8 + jj];
                #pragma unroll
                for (int i = 0; i < 7; i++) z = fmaf(q[i], w0v[i][jj], z);
                float h = sig(z);
                hv[jj] = h; dv[jj] = h - h * h;
            }
            int kt = k8 >> 2, kq = k8 & 3, sw = kt & 7;
            int rr0 = s * 8;
            {
                short8 v;
                #pragma unroll
                for (int jj = 0; jj < 8; jj++) v[jj] = (short)f2bf(hv[jj]);
                *(short8*)&sA[((rr0 >> 4) * 16 + kt) * 512 + ((kq * 16 + (rr0 & 15)) ^ sw) * 8] = v;
            }
            #pragma unroll
            for (int i = 0; i < 7; i++) {
                int rr = rr0 + 1 + i;
                short8 v;
                #pragma unroll
                for (int jj = 0; jj < 8; jj++) v[jj] = (short)f2bf(dv[jj] * w0v[i][jj]);
                *(short8*)&sA[((rr >> 4) * 16 + kt) * 512 + ((kq * 16 + (rr & 15)) ^ sw) * 8] = v;
            }
        }
        __syncthreads();

        floatx4 acc[4][8];
        #pragma unroll
        for (int rt = 0; rt < 4; rt++)
            #pragma unroll
            for (int ct = 0; ct < 8; ct++) acc[rt][ct] = z4;

        const short8* bbase = (const short8*)wsW1 + (size_t)(w * 8 * 16) * 64 + lane;
        short8 bufA[8], bufB[8];
        #pragma unroll
        for (int ct = 0; ct < 8; ++ct) bufA[ct] = bbase[(ct * 16) * 64];

        for (int kt2 = 0; kt2 < 16; kt2 += 2) {
            #pragma unroll
            for (int ct = 0; ct < 8; ++ct) bufB[ct] = bbase[(ct * 16 + kt2 + 1) * 64];
            {
                const int kt = kt2, sw = kt & 7;
                short8 afr[4];
                #pragma unroll
                for (int rt = 0; rt < 4; ++rt)
                    afr[rt] = *(const short8*)&sA[(rt * 16 + kt) * 512 + (lane ^ sw) * 8];
                #pragma unroll
                for (int ct = 0; ct < 8; ++ct)
                    #pragma unroll
                    for (int rt = 0; rt < 4; ++rt)
                        acc[rt][ct] = __builtin_amdgcn_mfma_f32_16x16x32_bf16(afr[rt], bufA[ct], acc[rt][ct], 0, 0, 0);
            }
            if (kt2 + 2 < 16) {
                #pragma unroll
                for (int ct = 0; ct < 8; ++ct) bufA[ct] = bbase[(ct * 16 + kt2 + 2) * 64];
            }
            {
                const int kt = kt2 + 1, sw = kt & 7;
                short8 afr[4];
                #pragma unroll
                for (int rt = 0; rt < 4; ++rt)
                    afr[rt] = *(const short8*)&sA[(rt * 16 + kt) * 512 + (lane ^ sw) * 8];
                #pragma unroll
                for (int ct = 0; ct < 8; ++ct)
                    #pragma unroll
                    for (int rt = 0; rt < 4; ++rt)
                        acc[rt][ct] = __builtin_amdgcn_mfma_f32_16x16x32_bf16(afr[rt], bufB[ct], acc[rt][ct], 0, 0, 0);
            }
        }

        float ep[4][4][3];
        #pragma unroll
        for (int a = 0; a < 4; a++) for (int b = 0; b < 4; b++) for (int c = 0; c < 3; c++) ep[a][b][c] = 0.f;

        #pragma unroll
        for (int ct = 0; ct < 8; ++ct) {
            const int n = w * 128 + ct * 16 + col;
            const float b1n = sU.p.B1[n];
            const float w20 = sU.p.W2[n * 3], w21 = sU.p.W2[n * 3 + 1], w22 = sU.p.W2[n * 3 + 2];
            #pragma unroll
            for (int rt = 0; rt < 4; ++rt) {
                float z2c = __shfl(acc[rt][ct][0], srcl);
                float h2 = sig(z2c + b1n);
                float d2 = h2 - h2 * h2;
                #pragma unroll
                for (int r = 0; r < 4; ++r) {
                    float gg = ((quad & 1) == 0 && r == 0) ? h2 : d2 * acc[rt][ct][r];
                    ep[rt][r][0] = fmaf(gg, w20, ep[rt][r][0]);
                    ep[rt][r][1] = fmaf(gg, w21, ep[rt][r][1]);
                    ep[rt][r][2] = fmaf(gg, w22, ep[rt][r][2]);
                }
            }
        }

        #pragma unroll
        for (int mask = 1; mask <= 8; mask <<= 1)
            #pragma unroll
            for (int a = 0; a < 4; a++)
                #pragma unroll
                for (int b = 0; b < 4; b++)
                    #pragma unroll
                    for (int c = 0; c < 3; c++)
                        ep[a][b][c] += __shfl_xor(ep[a][b][c], mask);
        if (col == 0) {
            #pragma unroll
            for (int rt = 0; rt < 4; ++rt)
                #pragma unroll
                for (int r = 0; r < 4; ++r) {
                    int row = rt * 16 + quad * 4 + r;
                    sU.p.Acc[w][row][0] = ep[rt][r][0];
                    sU.p.Acc[w][row][1] = ep[rt][r][1];
                    sU.p.Acc[w][row][2] = ep[rt][r][2];
                }
        }
        __syncthreads();

        if (tid < 192) {
            int row = tid / 3, j = tid % 3;
            float v = sU.p.Acc[0][row][j] + sU.p.Acc[1][row][j] + sU.p.Acc[2][row][j] + sU.p.Acc[3][row][j];
            int s = row >> 3, i = row & 7;
            size_t M = m0 + s;
            if (i == 0) { v += pb2[j]; out[M * 18 + j] = v; out[OUTA + M * 6 + j] = v; }
            else        { out[JTOT + M * 63 + j * 7 + (i - 1)] = v;
                          out[JANG + M * 42 + j * 7 + (i - 1)] = v; }
            sU.p.Sum[row][j] = v;
        }
        __syncthreads();
        if (tid < 24) {
            int s = tid / 3, j = tid % 3;
            float vel = 0.f;
            #pragma unroll
            for (int i = 0; i < 7; i++) vel = fmaf(sU.p.Sum[s * 8 + 1 + i][j], sU.p.Qd[s][i], vel);
            out[(size_t)(m0 + s) * 18 + 9 + j] = vel;
        }
    } else {
        // ================= RPY: 7 -> 256 -> 256 -> 2, 16 samples =================
        const int h = r5 - 2;
        const int m0 = g * 16;
        const float* W0 = (h == 0) ? rW0_ : (h == 1) ? piW0 : yW0;
        const float* b0 = (h == 0) ? rb0_ : (h == 1) ? pib0 : yb0;
        const float* b1 = (h == 0) ? rb1_ : (h == 1) ? pib1 : yb1;
        const float* W2 = (h == 0) ? rW2_ : (h == 1) ? piW2 : yW2;
        const float* b2 = (h == 0) ? rb2_ : (h == 1) ? pib2 : yb2;
        const unsigned short* wsW1 = wsBase + 262144 + h * 65536;

        if (tid < 256) { sU.r.B0[tid] = b0[tid]; sU.r.B1[tid] = b1[tid]; }
        for (int i = tid; i < 512; i += 256) sU.r.W2[i] = W2[i];
        if (tid < 224) {
            int m = tid / 14, c = tid % 14;
            float v = x[(m0 + m) * 14 + c];
            if (c < 7) sU.r.Q[m][c] = v; else sU.r.Qd[m][c - 7] = v;
        }
        __syncthreads();

        const float4* W04 = (const float4*)W0;
        #pragma unroll
        for (int t = 0; t < 2; ++t) {
            int item = tid + t * 256;
            int s = item >> 5, k8 = item & 31;
            float q[7], w0v[7][8];
            #pragma unroll
            for (int i = 0; i < 7; i++) {
                q[i] = sU.r.Q[s][i];
                float4 a = W04[i * 64 + k8 * 2], b4 = W04[i * 64 + k8 * 2 + 1];
                w0v[i][0]=a.x; w0v[i][1]=a.y; w0v[i][2]=a.z; w0v[i][3]=a.w;
                w0v[i][4]=b4.x; w0v[i][5]=b4.y; w0v[i][6]=b4.z; w0v[i][7]=b4.w;
            }
            float hv[8], dv[8];
            #pragma unroll
            for (int jj = 0; jj < 8; jj++) {
                float z = sU.r.B0[k8 * 8 + jj];
                #pragma unroll
                for (int i = 0; i < 7; i++) z = fmaf(q[i], w0v[i][jj], z);
                float hh = sig(z);
                hv[jj] = hh; dv[jj] = hh - hh * hh;
            }
            int kt = k8 >> 2, kq = k8 & 3, sw = kt & 7;
            int rr0 = s * 8;
            {
                short8 v;
                #pragma unroll
                for (int jj = 0; jj < 8; jj++) v[jj] = (short)f2bf(hv[jj]);
                *(short8*)&sA[((rr0 >> 4) * 8 + kt) * 512 + ((kq * 16 + (rr0 & 15)) ^ sw) * 8] = v;
            }
            #pragma unroll
            for (int i = 0; i < 7; i++) {
                int rr = rr0 + 1 + i;
                short8 v;
                #pragma unroll
                for (int jj = 0; jj < 8; jj++) v[jj] = (short)f2bf(dv[jj] * w0v[i][jj]);
                *(short8*)&sA[((rr >> 4) * 8 + kt) * 512 + ((kq * 16 + (rr & 15)) ^ sw) * 8] = v;
            }
        }
        __syncthreads();

        floatx4 acc[8][4];
        #pragma unroll
        for (int rt = 0; rt < 8; rt++)
            #pragma unroll
            for (int ct = 0; ct < 4; ct++) acc[rt][ct] = z4;

        const short8* bbase = (const short8*)wsW1 + (size_t)(w * 4 * 8) * 64 + lane;
        short8 bufA[4], bufB[4];
        #pragma unroll
        for (int ct = 0; ct < 4; ++ct) bufA[ct] = bbase[(ct * 8) * 64];

        for (int kt2 = 0; kt2 < 8; kt2 += 2) {
            #pragma unroll
            for (int ct = 0; ct < 4; ++ct) bufB[ct] = bbase[(ct * 8 + kt2 + 1) * 64];
            {
                const int kt = kt2, sw = kt & 7;
                short8 afr[8];
                #pragma unroll
                for (int rt = 0; rt < 8; ++rt)
                    afr[rt] = *(const short8*)&sA[(rt * 8 + kt) * 512 + (lane ^ sw) * 8];
                #pragma unroll
                for (int ct = 0; ct < 4; ++ct)
                    #pragma unroll
                    for (int rt = 0; rt < 8; ++rt)
                        acc[rt][ct] = __builtin_amdgcn_mfma_f32_16x16x32_bf16(afr[rt], bufA[ct], acc[rt][ct], 0, 0, 0);
            }
            if (kt2 + 2 < 8) {
                #pragma unroll
                for (int ct = 0; ct < 4; ++ct) bufA[ct] = bbase[(ct * 8 + kt2 + 2) * 64];
            }
            {
                const int kt = kt2 + 1, sw = kt & 7;
                short8 afr[8];
                #pragma unroll
                for (int rt = 0; rt < 8; ++rt)
                    afr[rt] = *(const short8*)&sA[(rt * 8 + kt) * 512 + (lane ^ sw) * 8];
                #pragma unroll
                for (int ct = 0; ct < 4; ++ct)
                    #pragma unroll
                    for (int rt = 0; rt < 8; ++rt)
                        acc[rt][ct] = __builtin_amdgcn_mfma_f32_16x16x32_bf16(afr[rt], bufB[ct], acc[rt][ct], 0, 0, 0);
            }
        }

        float ep[8][4][2];
        #pragma unroll
        for (int a = 0; a < 8; a++) for (int b = 0; b < 4; b++) for (int c = 0; c < 2; c++) ep[a][b][c] = 0.f;

        #pragma unroll
        for (int ct = 0; ct < 4; ++ct) {
            const int n = w * 64 + ct * 16 + col;
            const float b1n = sU.r.B1[n];
            const float w20 = sU.r.W2[n * 2], w21 = sU.r.W2[n * 2 + 1];
            #pragma unroll
            for (int rt = 0; rt < 8; ++rt) {
                float z2c = __shfl(acc[rt][ct][0], srcl);
                float h2 = sig(z2c + b1n);
                float d2 = h2 - h2 * h2;
                #pragma unroll
                for (int r = 0; r < 4; ++r) {
                    float gg = ((quad & 1) == 0 && r == 0) ? h2 : d2 * acc[rt][ct][r];
                    ep[rt][r][0] = fmaf(gg, w20, ep[rt][r][0]);
                    ep[rt][r][1] = fmaf(gg, w21, ep[rt][r][1]);
                }
            }
        }

        #pragma unroll
        for (int mask = 1; mask <= 8; mask <<= 1)
            #pragma unroll
            for (int a = 0; a < 8; a++)
                #pragma unroll
                for (int b = 0; b < 4; b++)
                    #pragma unroll
                    for (int c = 0; c < 2; c++)
                        ep[a][b][c] += __shfl_xor(ep[a][b][c], mask);
        if (col == 0) {
            #pragma unroll
            for (int rt = 0; rt < 8; ++rt)
                #pragma unroll
                for (int r = 0; r < 4; ++r) {
                    int row = rt * 16 + quad * 4 + r;
                    sU.r.Acc[w][row][0] = ep[rt][r][0];
                    sU.r.Acc[w][row][1] = ep[rt][r][1];
                }
        }
        __syncthreads();

        if (tid < 256) {
            int row = tid >> 1, j = tid & 1;
            float v = sU.r.Acc[0][row][j] + sU.r.Acc[1][row][j] + sU.r.Acc[2][row][j] + sU.r.Acc[3][row][j];
            if ((row & 7) == 0) v += b2[j];
            sU.r.Sum[row][j] = v;
        }
        __syncthreads();

        if (tid < 16) {
            int s = tid;
            size_t M = m0 + s;
            float y0 = sU.r.Sum[s * 8][0], y1 = sU.r.Sum[s * 8][1];
            float sv = sinf(y0), cv = cosf(y1);
            out[M * 18 + 3 + h] = sv;
            out[M * 18 + 6 + h] = cv;
            out[OUTA + M * 6 + 3 + h] = atan2f(sv, cv);
            float f0 = cosf(y0), f1 = -sinf(y1);
            float inv = 1.0f / fmaf(sv, sv, cv * cv);
            float v0 = 0.f, v1 = 0.f;
            #pragma unroll
            for (int i = 0; i < 7; i++) {
                float r0 = f0 * sU.r.Sum[s * 8 + 1 + i][0];
                float r1 = f1 * sU.r.Sum[s * 8 + 1 + i][1];
                out[JTOT + M * 63 + (3 + h) * 7 + i] = r0;
                out[JTOT + M * 63 + (6 + h) * 7 + i] = r1;
                out[JANG + M * 42 + (3 + h) * 7 + i] = (cv * r0 - sv * r1) * inv;
                v0 = fmaf(r0, sU.r.Qd[s][i], v0);
                v1 = fmaf(r1, sU.r.Qd[s][i], v1);
            }
            out[M * 18 + 12 + h] = v0;
            out[M * 18 + 15 + h] = v1;
        }
    }
}

extern "C" void kernel_launch(void* const* d_in, const int* in_sizes, int n_in,
                              void* d_out, int out_size, void* d_ws, size_t ws_size,
                              hipStream_t stream) {
    (void)n_in; (void)out_size; (void)ws_size;
    const float* x = (const float*)d_in[0];
    float* out = (float*)d_out;
    unsigned short* ws = (unsigned short*)d_ws;
    const int ns = in_sizes[0] / 14;

    convert_all<<<dim3(1792), 256, 0, stream>>>(
        (const float*)d_in[3], (const float*)d_in[9],
        (const float*)d_in[15], (const float*)d_in[21], ws);

    // 5120 blocks; XCD-colocated remap done inside the kernel
    fused_mfma<<<dim3((ns / 8 / 2) * 5), 256, 65536, stream>>>(
        x,
        (const float*)d_in[1],  (const float*)d_in[2],  (const float*)d_in[4],
        (const float*)d_in[5],  (const float*)d_in[6],
        (const float*)d_in[7],  (const float*)d_in[8],  (const float*)d_in[10],
        (const float*)d_in[11], (const float*)d_in[12],
        (const float*)d_in[13], (const float*)d_in[14], (const float*)d_in[16],
        (const float*)d_in[17], (const float*)d_in[18],
        (const float*)d_in[19], (const float*)d_in[20], (const float*)d_in[22],
        (const float*)d_in[23], (const float*)d_in[24],
        ws, out, ns);
}

// Round 14
// 329.510 us; speedup vs baseline: 2.5766x; 1.0067x over previous
//
#include <hip/hip_runtime.h>
#include <math.h>

typedef __attribute__((ext_vector_type(8))) short short8;
typedef __attribute__((ext_vector_type(4))) float floatx4;

__device__ __forceinline__ float sig(float z) { return 1.0f / (1.0f + __expf(-z)); }

__device__ __forceinline__ unsigned short f2bf(float f) {
    unsigned u = __float_as_uint(f);
    u = (u + 0x7FFFu + ((u >> 16) & 1u)) >> 16;   // RNE
    return (unsigned short)u;
}

// All four W1 matrices -> bf16 pre-swizzled MFMA 16x16x32 B-frag order.
// blk = (n>>4)*(H/32) + (k>>5), lane = ((k>>3)&3)*16 + (n&15), j = k&7.
// NOTE: this is the per-element version (one 2B store per thread). A coalesced
// wave-per-fragment-block rewrite (R13) caused intermittent post-timing
// divergence (stale ws lines on some graph replays) despite identical mapping —
// reverted to this 12/12-passing version. It costs only ~4 us (measured R13).
__global__ void convert_all(const float* __restrict__ s0, const float* __restrict__ s1,
                            const float* __restrict__ s2, const float* __restrict__ s3,
                            unsigned short* __restrict__ ws) {
    int idx = blockIdx.x * 256 + threadIdx.x;          // 0 .. 458751
    const float* src; unsigned short* dst; int H, logH, local;
    if (idx < 262144) { src = s0; dst = ws; H = 512; logH = 9; local = idx; }
    else {
        int r = idx - 262144; int m = r >> 16; local = r & 65535;
        H = 256; logH = 8;
        src = (m == 0) ? s1 : (m == 1) ? s2 : s3;
        dst = ws + 262144 + m * 65536;
    }
    int n = local & (H - 1), k = local >> logH;
    int KT = H >> 5;
    int blk = (n >> 4) * KT + (k >> 5);
    int lane = ((k >> 3) & 3) * 16 + (n & 15);
    int j = k & 7;
    dst[(blk * 64 + lane) * 8 + j] = f2bf(src[local]);
}

struct PosS {
    float B0[512], B1[512], W2[1536];
    float Q[8][8], Qd[8][8];
    float Acc[4][64][3], Sum[64][3];
};
struct RpyS {
    float B0[256], B1[256], W2[512];
    float Q[16][8], Qd[16][8];
    float Acc[4][128][2], Sum[128][2];
};

// Fused kernel (R12 body, measured 331.7 us total / 255.7 us dispatch):
// 5120 blocks; role r5<2 -> pos tile (8 samples), r5>=2 -> rpy head (16 samples).
// XCD-colocated remap: all 5 roles of sample-group g land on XCD g%8 so the four
// co-writers of each output cache line share one L2 (verified: WRITE 38->21 MB).
__global__ __launch_bounds__(256, 2)
void fused_mfma(const float* __restrict__ x,
                const float* __restrict__ pW0, const float* __restrict__ pb0,
                const float* __restrict__ pb1,
                const float* __restrict__ pW2, const float* __restrict__ pb2,
                const float* __restrict__ rW0_, const float* __restrict__ rb0_,
                const float* __restrict__ rb1_,
                const float* __restrict__ rW2_, const float* __restrict__ rb2_,
                const float* __restrict__ piW0, const float* __restrict__ pib0,
                const float* __restrict__ pib1,
                const float* __restrict__ piW2, const float* __restrict__ pib2,
                const float* __restrict__ yW0, const float* __restrict__ yb0,
                const float* __restrict__ yb1,
                const float* __restrict__ yW2, const float* __restrict__ yb2,
                const unsigned short* __restrict__ wsBase,
                float* __restrict__ out, int ns)
{
    extern __shared__ unsigned short sA[];      // 64 KB dynamic
    __shared__ union { PosS p; RpyS r; } sU;

    const int tid = threadIdx.x;
    const int xcd  = blockIdx.x & 7;
    const int slot = blockIdx.x >> 3;           // 0..639 within this XCD
    const int gidx = slot / 5, r5 = slot % 5;
    const int g = xcd + (gidx << 3);            // group 0..1023

    const size_t JTOT = (size_t)ns * 18, OUTA = (size_t)ns * 81, JANG = (size_t)ns * 87;
    const floatx4 z4 = {0.f, 0.f, 0.f, 0.f};
    const int w = tid >> 6, lane = tid & 63;
    const int quad = lane >> 4, col = lane & 15;
    const int srcl = lane & 47;

    if (r5 < 2) {
        // ================= POS: 7 -> 512 -> 512 -> 3, 8 samples =================
        const int m0 = (g * 2 + r5) * 8;
        const unsigned short* wsW1 = wsBase;

        for (int i = tid; i < 512;  i += 256) { sU.p.B0[i] = pb0[i]; sU.p.B1[i] = pb1[i]; }
        for (int i = tid; i < 1536; i += 256) sU.p.W2[i] = pW2[i];
        if (tid < 112) {
            int m = tid / 14, c = tid % 14;
            float v = x[(m0 + m) * 14 + c];
            if (c < 7) sU.p.Q[m][c] = v; else sU.p.Qd[m][c - 7] = v;
        }
        __syncthreads();

        const float4* W04 = (const float4*)pW0;
        #pragma unroll
        for (int t = 0; t < 2; ++t) {
            int item = tid + t * 256;
            int s = item >> 6, k8 = item & 63;
            float q[7], w0v[7][8];
            #pragma unroll
            for (int i = 0; i < 7; i++) {
                q[i] = sU.p.Q[s][i];
                float4 a = W04[i * 128 + k8 * 2], b4 = W04[i * 128 + k8 * 2 + 1];
                w0v[i][0]=a.x; w0v[i][1]=a.y; w0v[i][2]=a.z; w0v[i][3]=a.w;
                w0v[i][4]=b4.x; w0v[i][5]=b4.y; w0v[i][6]=b4.z; w0v[i][7]=b4.w;
            }
            float hv[8], dv[8];
            #pragma unroll
            for (int jj = 0; jj < 8; jj++) {
                float z = sU.p.B0[k8 * 8 + jj];
                #pragma unroll
                for (int i = 0; i < 7; i++) z = fmaf(q[i], w0v[i][jj], z);
                float h = sig(z);
                hv[jj] = h; dv[jj] = h - h * h;
            }
            int kt = k8 >> 2, kq = k8 & 3, sw = kt & 7;
            int rr0 = s * 8;
            {
                short8 v;
                #pragma unroll
                for (int jj = 0; jj < 8; jj++) v[jj] = (short)f2bf(hv[jj]);
                *(short8*)&sA[((rr0 >> 4) * 16 + kt) * 512 + ((kq * 16 + (rr0 & 15)) ^ sw) * 8] = v;
            }
            #pragma unroll
            for (int i = 0; i < 7; i++) {
                int rr = rr0 + 1 + i;
                short8 v;
                #pragma unroll
                for (int jj = 0; jj < 8; jj++) v[jj] = (short)f2bf(dv[jj] * w0v[i][jj]);
                *(short8*)&sA[((rr >> 4) * 16 + kt) * 512 + ((kq * 16 + (rr & 15)) ^ sw) * 8] = v;
            }
        }
        __syncthreads();

        floatx4 acc[4][8];
        #pragma unroll
        for (int rt = 0; rt < 4; rt++)
            #pragma unroll
            for (int ct = 0; ct < 8; ct++) acc[rt][ct] = z4;

        const short8* bbase = (const short8*)wsW1 + (size_t)(w * 8 * 16) * 64 + lane;
        short8 bufA[8], bufB[8];
        #pragma unroll
        for (int ct = 0; ct < 8; ++ct) bufA[ct] = bbase[(ct * 16) * 64];

        for (int kt2 = 0; kt2 < 16; kt2 += 2) {
            #pragma unroll
            for (int ct = 0; ct < 8; ++ct) bufB[ct] = bbase[(ct * 16 + kt2 + 1) * 64];
            {
                const int kt = kt2, sw = kt & 7;
                short8 afr[4];
                #pragma unroll
                for (int rt = 0; rt < 4; ++rt)
                    afr[rt] = *(const short8*)&sA[(rt * 16 + kt) * 512 + (lane ^ sw) * 8];
                #pragma unroll
                for (int ct = 0; ct < 8; ++ct)
                    #pragma unroll
                    for (int rt = 0; rt < 4; ++rt)
                        acc[rt][ct] = __builtin_amdgcn_mfma_f32_16x16x32_bf16(afr[rt], bufA[ct], acc[rt][ct], 0, 0, 0);
            }
            if (kt2 + 2 < 16) {
                #pragma unroll
                for (int ct = 0; ct < 8; ++ct) bufA[ct] = bbase[(ct * 16 + kt2 + 2) * 64];
            }
            {
                const int kt = kt2 + 1, sw = kt & 7;
                short8 afr[4];
                #pragma unroll
                for (int rt = 0; rt < 4; ++rt)
                    afr[rt] = *(const short8*)&sA[(rt * 16 + kt) * 512 + (lane ^ sw) * 8];
                #pragma unroll
                for (int ct = 0; ct < 8; ++ct)
                    #pragma unroll
                    for (int rt = 0; rt < 4; ++rt)
                        acc[rt][ct] = __builtin_amdgcn_mfma_f32_16x16x32_bf16(afr[rt], bufB[ct], acc[rt][ct], 0, 0, 0);
            }
        }

        float ep[4][4][3];
        #pragma unroll
        for (int a = 0; a < 4; a++) for (int b = 0; b < 4; b++) for (int c = 0; c < 3; c++) ep[a][b][c] = 0.f;

        #pragma unroll
        for (int ct = 0; ct < 8; ++ct) {
            const int n = w * 128 + ct * 16 + col;
            const float b1n = sU.p.B1[n];
            const float w20 = sU.p.W2[n * 3], w21 = sU.p.W2[n * 3 + 1], w22 = sU.p.W2[n * 3 + 2];
            #pragma unroll
            for (int rt = 0; rt < 4; ++rt) {
                float z2c = __shfl(acc[rt][ct][0], srcl);
                float h2 = sig(z2c + b1n);
                float d2 = h2 - h2 * h2;
                #pragma unroll
                for (int r = 0; r < 4; ++r) {
                    float gg = ((quad & 1) == 0 && r == 0) ? h2 : d2 * acc[rt][ct][r];
                    ep[rt][r][0] = fmaf(gg, w20, ep[rt][r][0]);
                    ep[rt][r][1] = fmaf(gg, w21, ep[rt][r][1]);
                    ep[rt][r][2] = fmaf(gg, w22, ep[rt][r][2]);
                }
            }
        }

        #pragma unroll
        for (int mask = 1; mask <= 8; mask <<= 1)
            #pragma unroll
            for (int a = 0; a < 4; a++)
                #pragma unroll
                for (int b = 0; b < 4; b++)
                    #pragma unroll
                    for (int c = 0; c < 3; c++)
                        ep[a][b][c] += __shfl_xor(ep[a][b][c], mask);
        if (col == 0) {
            #pragma unroll
            for (int rt = 0; rt < 4; ++rt)
                #pragma unroll
                for (int r = 0; r < 4; ++r) {
                    int row = rt * 16 + quad * 4 + r;
                    sU.p.Acc[w][row][0] = ep[rt][r][0];
                    sU.p.Acc[w][row][1] = ep[rt][r][1];
                    sU.p.Acc[w][row][2] = ep[rt][r][2];
                }
        }
        __syncthreads();

        if (tid < 192) {
            int row = tid / 3, j = tid % 3;
            float v = sU.p.Acc[0][row][j] + sU.p.Acc[1][row][j] + sU.p.Acc[2][row][j] + sU.p.Acc[3][row][j];
            int s = row >> 3, i = row & 7;
            size_t M = m0 + s;
            if (i == 0) { v += pb2[j]; out[M * 18 + j] = v; out[OUTA + M * 6 + j] = v; }
            else        { out[JTOT + M * 63 + j * 7 + (i - 1)] = v;
                          out[JANG + M * 42 + j * 7 + (i - 1)] = v; }
            sU.p.Sum[row][j] = v;
        }
        __syncthreads();
        if (tid < 24) {
            int s = tid / 3, j = tid % 3;
            float vel = 0.f;
            #pragma unroll
            for (int i = 0; i < 7; i++) vel = fmaf(sU.p.Sum[s * 8 + 1 + i][j], sU.p.Qd[s][i], vel);
            out[(size_t)(m0 + s) * 18 + 9 + j] = vel;
        }
    } else {
        // ================= RPY: 7 -> 256 -> 256 -> 2, 16 samples =================
        const int h = r5 - 2;
        const int m0 = g * 16;
        const float* W0 = (h == 0) ? rW0_ : (h == 1) ? piW0 : yW0;
        const float* b0 = (h == 0) ? rb0_ : (h == 1) ? pib0 : yb0;
        const float* b1 = (h == 0) ? rb1_ : (h == 1) ? pib1 : yb1;
        const float* W2 = (h == 0) ? rW2_ : (h == 1) ? piW2 : yW2;
        const float* b2 = (h == 0) ? rb2_ : (h == 1) ? pib2 : yb2;
        const unsigned short* wsW1 = wsBase + 262144 + h * 65536;

        if (tid < 256) { sU.r.B0[tid] = b0[tid]; sU.r.B1[tid] = b1[tid]; }
        for (int i = tid; i < 512; i += 256) sU.r.W2[i] = W2[i];
        if (tid < 224) {
            int m = tid / 14, c = tid % 14;
            float v = x[(m0 + m) * 14 + c];
            if (c < 7) sU.r.Q[m][c] = v; else sU.r.Qd[m][c - 7] = v;
        }
        __syncthreads();

        const float4* W04 = (const float4*)W0;
        #pragma unroll
        for (int t = 0; t < 2; ++t) {
            int item = tid + t * 256;
            int s = item >> 5, k8 = item & 31;
            float q[7], w0v[7][8];
            #pragma unroll
            for (int i = 0; i < 7; i++) {
                q[i] = sU.r.Q[s][i];
                float4 a = W04[i * 64 + k8 * 2], b4 = W04[i * 64 + k8 * 2 + 1];
                w0v[i][0]=a.x; w0v[i][1]=a.y; w0v[i][2]=a.z; w0v[i][3]=a.w;
                w0v[i][4]=b4.x; w0v[i][5]=b4.y; w0v[i][6]=b4.z; w0v[i][7]=b4.w;
            }
            float hv[8], dv[8];
            #pragma unroll
            for (int jj = 0; jj < 8; jj++) {
                float z = sU.r.B0[k8 * 8 + jj];
                #pragma unroll
                for (int i = 0; i < 7; i++) z = fmaf(q[i], w0v[i][jj], z);
                float hh = sig(z);
                hv[jj] = hh; dv[jj] = hh - hh * hh;
            }
            int kt = k8 >> 2, kq = k8 & 3, sw = kt & 7;
            int rr0 = s * 8;
            {
                short8 v;
                #pragma unroll
                for (int jj = 0; jj < 8; jj++) v[jj] = (short)f2bf(hv[jj]);
                *(short8*)&sA[((rr0 >> 4) * 8 + kt) * 512 + ((kq * 16 + (rr0 & 15)) ^ sw) * 8] = v;
            }
            #pragma unroll
            for (int i = 0; i < 7; i++) {
                int rr = rr0 + 1 + i;
                short8 v;
                #pragma unroll
                for (int jj = 0; jj < 8; jj++) v[jj] = (short)f2bf(dv[jj] * w0v[i][jj]);
                *(short8*)&sA[((rr >> 4) * 8 + kt) * 512 + ((kq * 16 + (rr & 15)) ^ sw) * 8] = v;
            }
        }
        __syncthreads();

        floatx4 acc[8][4];
        #pragma unroll
        for (int rt = 0; rt < 8; rt++)
            #pragma unroll
            for (int ct = 0; ct < 4; ct++) acc[rt][ct] = z4;

        const short8* bbase = (const short8*)wsW1 + (size_t)(w * 4 * 8) * 64 + lane;
        short8 bufA[4], bufB[4];
        #pragma unroll
        for (int ct = 0; ct < 4; ++ct) bufA[ct] = bbase[(ct * 8) * 64];

        for (int kt2 = 0; kt2 < 8; kt2 += 2) {
            #pragma unroll
            for (int ct = 0; ct < 4; ++ct) bufB[ct] = bbase[(ct * 8 + kt2 + 1) * 64];
            {
                const int kt = kt2, sw = kt & 7;
                short8 afr[8];
                #pragma unroll
                for (int rt = 0; rt < 8; ++rt)
                    afr[rt] = *(const short8*)&sA[(rt * 8 + kt) * 512 + (lane ^ sw) * 8];
                #pragma unroll
                for (int ct = 0; ct < 4; ++ct)
                    #pragma unroll
                    for (int rt = 0; rt < 8; ++rt)
                        acc[rt][ct] = __builtin_amdgcn_mfma_f32_16x16x32_bf16(afr[rt], bufA[ct], acc[rt][ct], 0, 0, 0);
            }
            if (kt2 + 2 < 8) {
                #pragma unroll
                for (int ct = 0; ct < 4; ++ct) bufA[ct] = bbase[(ct * 8 + kt2 + 2) * 64];
            }
            {
                const int kt = kt2 + 1, sw = kt & 7;
                short8 afr[8];
                #pragma unroll
                for (int rt = 0; rt < 8; ++rt)
                    afr[rt] = *(const short8*)&sA[(rt * 8 + kt) * 512 + (lane ^ sw) * 8];
                #pragma unroll
                for (int ct = 0; ct < 4; ++ct)
                    #pragma unroll
                    for (int rt = 0; rt < 8; ++rt)
                        acc[rt][ct] = __builtin_amdgcn_mfma_f32_16x16x32_bf16(afr[rt], bufB[ct], acc[rt][ct], 0, 0, 0);
            }
        }

        float ep[8][4][2];
        #pragma unroll
        for (int a = 0; a < 8; a++) for (int b = 0; b < 4; b++) for (int c = 0; c < 2; c++) ep[a][b][c] = 0.f;

        #pragma unroll
        for (int ct = 0; ct < 4; ++ct) {
            const int n = w * 64 + ct * 16 + col;
            const float b1n = sU.r.B1[n];
            const float w20 = sU.r.W2[n * 2], w21 = sU.r.W2[n * 2 + 1];
            #pragma unroll
            for (int rt = 0; rt < 8; ++rt) {
                float z2c = __shfl(acc[rt][ct][0], srcl);
                float h2 = sig(z2c + b1n);
                float d2 = h2 - h2 * h2;
                #pragma unroll
                for (int r = 0; r < 4; ++r) {
                    float gg = ((quad & 1) == 0 && r == 0) ? h2 : d2 * acc[rt][ct][r];
                    ep[rt][r][0] = fmaf(gg, w20, ep[rt][r][0]);
                    ep[rt][r][1] = fmaf(gg, w21, ep[rt][r][1]);
                }
            }
        }

        #pragma unroll
        for (int mask = 1; mask <= 8; mask <<= 1)
            #pragma unroll
            for (int a = 0; a < 8; a++)
                #pragma unroll
                for (int b = 0; b < 4; b++)
                    #pragma unroll
                    for (int c = 0; c < 2; c++)
                        ep[a][b][c] += __shfl_xor(ep[a][b][c], mask);
        if (col == 0) {
            #pragma unroll
            for (int rt = 0; rt < 8; ++rt)
                #pragma unroll
                for (int r = 0; r < 4; ++r) {
                    int row = rt * 16 + quad * 4 + r;
                    sU.r.Acc[w][row][0] = ep[rt][r][0];
                    sU.r.Acc[w][row][1] = ep[rt][r][1];
                }
        }
        __syncthreads();

        if (tid < 256) {
            int row = tid >> 1, j = tid & 1;
            float v = sU.r.Acc[0][row][j] + sU.r.Acc[1][row][j] + sU.r.Acc[2][row][j] + sU.r.Acc[3][row][j];
            if ((row & 7) == 0) v += b2[j];
            sU.r.Sum[row][j] = v;
        }
        __syncthreads();

        if (tid < 16) {
            int s = tid;
            size_t M = m0 + s;
            float y0 = sU.r.Sum[s * 8][0], y1 = sU.r.Sum[s * 8][1];
            float sv = sinf(y0), cv = cosf(y1);
            out[M * 18 + 3 + h] = sv;
            out[M * 18 + 6 + h] = cv;
            out[OUTA + M * 6 + 3 + h] = atan2f(sv, cv);
            float f0 = cosf(y0), f1 = -sinf(y1);
            float inv = 1.0f / fmaf(sv, sv, cv * cv);
            float v0 = 0.f, v1 = 0.f;
            #pragma unroll
            for (int i = 0; i < 7; i++) {
                float r0 = f0 * sU.r.Sum[s * 8 + 1 + i][0];
                float r1 = f1 * sU.r.Sum[s * 8 + 1 + i][1];
                out[JTOT + M * 63 + (3 + h) * 7 + i] = r0;
                out[JTOT + M * 63 + (6 + h) * 7 + i] = r1;
                out[JANG + M * 42 + (3 + h) * 7 + i] = (cv * r0 - sv * r1) * inv;
                v0 = fmaf(r0, sU.r.Qd[s][i], v0);
                v1 = fmaf(r1, sU.r.Qd[s][i], v1);
            }
            out[M * 18 + 12 + h] = v0;
            out[M * 18 + 15 + h] = v1;
        }
    }
}

extern "C" void kernel_launch(void* const* d_in, const int* in_sizes, int n_in,
                              void* d_out, int out_size, void* d_ws, size_t ws_size,
                              hipStream_t stream) {
    (void)n_in; (void)out_size; (void)ws_size;
    const float* x = (const float*)d_in[0];
    float* out = (float*)d_out;
    unsigned short* ws = (unsigned short*)d_ws;
    const int ns = in_sizes[0] / 14;

    convert_all<<<dim3(1792), 256, 0, stream>>>(
        (const float*)d_in[3], (const float*)d_in[9],
        (const float*)d_in[15], (const float*)d_in[21], ws);

    // 5120 blocks; XCD-colocated remap done inside the kernel
    fused_mfma<<<dim3((ns / 8 / 2) * 5), 256, 65536, stream>>>(
        x,
        (const float*)d_in[1],  (const float*)d_in[2],  (const float*)d_in[4],
        (const float*)d_in[5],  (const float*)d_in[6],
        (const float*)d_in[7],  (const float*)d_in[8],  (const float*)d_in[10],
        (const float*)d_in[11], (const float*)d_in[12],
        (const float*)d_in[13], (const float*)d_in[14], (const float*)d_in[16],
        (const float*)d_in[17], (const float*)d_in[18],
        (const float*)d_in[19], (const float*)d_in[20], (const float*)d_in[22],
        (const float*)d_in[23], (const float*)d_in[24],
        ws, out, ns);
}